// Round 4
// baseline (302.232 us; speedup 1.0000x reference)
//
#include <hip/hip_runtime.h>
#include <hip/hip_bf16.h>

// SlotAttention on MI355X. B=64, N=4096, Din=D=64, S=7, H=128, 3 iters.
// v4: request-rate attack — proj epilogue staged in LDS for coalesced 16B/lane
// stores; attn stages vT tile in LDS (PV B-frags via ds_read_b128); post is
// one block per batch (weights read once, amortized over 7 slots).

#define NB 64
#define NN 4096
#define NS 7
#define LN_EPS 1e-3f
#define EPS_ATTN 1e-8f

typedef __attribute__((ext_vector_type(8))) __bf16 bf16x8;
typedef __attribute__((ext_vector_type(8))) unsigned short u16x8;
typedef __attribute__((ext_vector_type(4))) float f32x4;
typedef __attribute__((ext_vector_type(4))) unsigned int u32x4;

__device__ __forceinline__ unsigned short f2bf(float f) {
    unsigned int x = __float_as_uint(f);
    x += 0x7FFFu + ((x >> 16) & 1u);
    return (unsigned short)(x >> 16);
}

__device__ __forceinline__ bf16x8 pack8(float4 a, float4 b) {
    u16x8 r;
    r[0] = f2bf(a.x); r[1] = f2bf(a.y); r[2] = f2bf(a.z); r[3] = f2bf(a.w);
    r[4] = f2bf(b.x); r[5] = f2bf(b.y); r[6] = f2bf(b.z); r[7] = f2bf(b.w);
    return __builtin_bit_cast(bf16x8, r);
}

// ---------------- prep: G^T = (g (.) W)^T bf16, colsums ----------------
__global__ __launch_bounds__(64) void prep_kernel(
        const float* __restrict__ Wk, const float* __restrict__ Wv,
        const float* __restrict__ g, const float* __restrict__ bb,
        unsigned short* __restrict__ GkT, unsigned short* __restrict__ GvT,
        float* __restrict__ cgk, float* __restrict__ cbk,
        float* __restrict__ cgv, float* __restrict__ cbv) {
    int j = blockIdx.x & 63, mat = blockIdx.x >> 6, d = threadIdx.x;
    const float* W = mat ? Wv : Wk;
    unsigned short* GT = mat ? GvT : GkT;
    float* cg = mat ? cgv : cgk;
    float* cb = mat ? cbv : cbk;
    float w = W[d * 64 + j];
    float gv = g[d], bv = bb[d];
    GT[j * 64 + d] = f2bf(gv * w);
    float sg = gv * w, sb = bv * w;
#pragma unroll
    for (int off = 1; off < 64; off <<= 1) {
        sg += __shfl_xor(sg, off);
        sb += __shfl_xor(sb, off);
    }
    if (d == 0) { cg[j] = sg; cb[j] = sb; }
}

// ---------------- init slots ----------------
__global__ void init_slots_kernel(const float* __restrict__ noise, const float* __restrict__ mu,
                                  const float* __restrict__ lsig, float* __restrict__ slots) {
    int idx = blockIdx.x * 256 + threadIdx.x;
    if (idx < NB * NS * 64) {
        int d = idx & 63;
        slots[idx] = mu[d] + __expf(lsig[d]) * noise[idx];
    }
}

// ---------------- proj: k (row-major), vT (d-major) = LN(x)@W; LDS-staged stores ----------------
__global__ __launch_bounds__(256) void proj_kernel(
        const float* __restrict__ x, const unsigned short* __restrict__ GkT,
        const unsigned short* __restrict__ GvT,
        const float* __restrict__ cgk, const float* __restrict__ cbk,
        const float* __restrict__ cgv, const float* __restrict__ cbv,
        unsigned short* __restrict__ kout, unsigned short* __restrict__ vT) {
    __shared__ __align__(16) unsigned short ktile[128 * 72];   // 18.4KB, [row][72]
    __shared__ __align__(16) unsigned short vtile[64 * 136];   // 17.4KB, [d][136]
    int t = threadIdx.x;
    int w = t >> 6, lane = t & 63;
    int h = lane >> 4, rl = lane & 15;
    long base = (long)blockIdx.x * 128;         // block = 128 rows
    int bb = blockIdx.x >> 5;                   // batch
    int nblk = (blockIdx.x & 31) * 128;         // n offset within batch
    const float* xr0 = x + (base + w * 16 + rl) * 64 + h * 8;
    const float* xr1 = xr0 + 64 * 64;
    float4 xa[8];
    xa[0] = *(const float4*)(xr0);      xa[1] = *(const float4*)(xr0 + 4);
    xa[2] = *(const float4*)(xr0 + 32); xa[3] = *(const float4*)(xr0 + 36);
    xa[4] = *(const float4*)(xr1);      xa[5] = *(const float4*)(xr1 + 4);
    xa[6] = *(const float4*)(xr1 + 32); xa[7] = *(const float4*)(xr1 + 36);
    float s1a = 0.f, s2a = 0.f, s1b = 0.f, s2b = 0.f;
#pragma unroll
    for (int i = 0; i < 4; ++i) {
        s1a += xa[i].x + xa[i].y + xa[i].z + xa[i].w;
        s2a += xa[i].x * xa[i].x + xa[i].y * xa[i].y + xa[i].z * xa[i].z + xa[i].w * xa[i].w;
        s1b += xa[4 + i].x + xa[4 + i].y + xa[4 + i].z + xa[4 + i].w;
        s2b += xa[4 + i].x * xa[4 + i].x + xa[4 + i].y * xa[4 + i].y + xa[4 + i].z * xa[4 + i].z + xa[4 + i].w * xa[4 + i].w;
    }
    s1a += __shfl_xor(s1a, 16); s2a += __shfl_xor(s2a, 16);
    s1a += __shfl_xor(s1a, 32); s2a += __shfl_xor(s2a, 32);
    s1b += __shfl_xor(s1b, 16); s2b += __shfl_xor(s2b, 16);
    s1b += __shfl_xor(s1b, 32); s2b += __shfl_xor(s2b, 32);
    float m0 = s1a * (1.f / 64.f);
    float i0 = rsqrtf(s2a * (1.f / 64.f) - m0 * m0 + LN_EPS);
    float m1 = s1b * (1.f / 64.f);
    float i1 = rsqrtf(s2b * (1.f / 64.f) - m1 * m1 + LN_EPS);
    bf16x8 a00 = pack8(xa[0], xa[1]), a01 = pack8(xa[2], xa[3]);
    bf16x8 a10 = pack8(xa[4], xa[5]), a11 = pack8(xa[6], xa[7]);
    f32x4 k0a[4], v0a[4], k1a[4], v1a[4];
#pragma unroll
    for (int nt = 0; nt < 4; ++nt) {
        k0a[nt] = (f32x4){0.f, 0.f, 0.f, 0.f}; v0a[nt] = (f32x4){0.f, 0.f, 0.f, 0.f};
        k1a[nt] = (f32x4){0.f, 0.f, 0.f, 0.f}; v1a[nt] = (f32x4){0.f, 0.f, 0.f, 0.f};
    }
#pragma unroll
    for (int nt = 0; nt < 4; ++nt) {
        const unsigned short* gk = GkT + (nt * 16 + rl) * 64 + h * 8;
        const unsigned short* gv = GvT + (nt * 16 + rl) * 64 + h * 8;
        bf16x8 bk0 = *(const bf16x8*)(gk);
        bf16x8 bk1 = *(const bf16x8*)(gk + 32);
        bf16x8 bv0 = *(const bf16x8*)(gv);
        bf16x8 bv1 = *(const bf16x8*)(gv + 32);
        k0a[nt] = __builtin_amdgcn_mfma_f32_16x16x32_bf16(a00, bk0, k0a[nt], 0, 0, 0);
        k0a[nt] = __builtin_amdgcn_mfma_f32_16x16x32_bf16(a01, bk1, k0a[nt], 0, 0, 0);
        v0a[nt] = __builtin_amdgcn_mfma_f32_16x16x32_bf16(a00, bv0, v0a[nt], 0, 0, 0);
        v0a[nt] = __builtin_amdgcn_mfma_f32_16x16x32_bf16(a01, bv1, v0a[nt], 0, 0, 0);
        k1a[nt] = __builtin_amdgcn_mfma_f32_16x16x32_bf16(a10, bk0, k1a[nt], 0, 0, 0);
        k1a[nt] = __builtin_amdgcn_mfma_f32_16x16x32_bf16(a11, bk1, k1a[nt], 0, 0, 0);
        v1a[nt] = __builtin_amdgcn_mfma_f32_16x16x32_bf16(a10, bv0, v1a[nt], 0, 0, 0);
        v1a[nt] = __builtin_amdgcn_mfma_f32_16x16x32_bf16(a11, bv1, v1a[nt], 0, 0, 0);
    }
    float mr0[4], ir0[4], mr1[4], ir1[4];
#pragma unroll
    for (int r = 0; r < 4; ++r) {
        int rlsrc = h * 4 + r;
        mr0[r] = __shfl(m0, rlsrc); ir0[r] = __shfl(i0, rlsrc);
        mr1[r] = __shfl(m1, rlsrc); ir1[r] = __shfl(i1, rlsrc);
    }
#pragma unroll
    for (int nt = 0; nt < 4; ++nt) {
        int j = nt * 16 + rl;
        float cgkj = cgk[j], cbkj = cbk[j], cgvj = cgv[j], cbvj = cbv[j];
        unsigned short vv0[4], vv1[4];
#pragma unroll
        for (int r = 0; r < 4; ++r) {
            int row = w * 16 + h * 4 + r;
            ktile[row * 72 + j] = f2bf(ir0[r] * (k0a[nt][r] - mr0[r] * cgkj) + cbkj);
            ktile[(64 + row) * 72 + j] = f2bf(ir1[r] * (k1a[nt][r] - mr1[r] * cgkj) + cbkj);
            vv0[r] = f2bf(ir0[r] * (v0a[nt][r] - mr0[r] * cgvj) + cbvj);
            vv1[r] = f2bf(ir1[r] * (v1a[nt][r] - mr1[r] * cgvj) + cbvj);
        }
        uint2 p0 = make_uint2((unsigned int)vv0[0] | ((unsigned int)vv0[1] << 16),
                              (unsigned int)vv0[2] | ((unsigned int)vv0[3] << 16));
        uint2 p1 = make_uint2((unsigned int)vv1[0] | ((unsigned int)vv1[1] << 16),
                              (unsigned int)vv1[2] | ((unsigned int)vv1[3] << 16));
        *(uint2*)(&vtile[j * 136 + w * 16 + h * 4]) = p0;
        *(uint2*)(&vtile[j * 136 + 64 + w * 16 + h * 4]) = p1;
    }
    __syncthreads();
    // coalesced stores: k 16KB, vT 16KB, 16B/lane contiguous
#pragma unroll
    for (int i = 0; i < 4; ++i) {
        int flat = (i * 256 + t) * 8;
        int row = flat >> 6, col = flat & 63;
        uint4 kd = *(const uint4*)(&ktile[row * 72 + col]);
        *(uint4*)(kout + (base + row) * 64 + col) = kd;
        int dd = flat >> 7, noff = flat & 127;
        uint4 vd = *(const uint4*)(&vtile[dd * 136 + noff]);
        *(uint4*)(vT + ((long)(bb * 64 + dd)) * NN + nblk + noff) = vd;
    }
}

// ---------------- slots_pre (iter 0): q = LN(slots)@Wq*scale, zero U,Z ----------------
__global__ __launch_bounds__(64) void slots_pre_kernel(
        const float* __restrict__ slots, const float* __restrict__ Wq,
        const float* __restrict__ lg, const float* __restrict__ lb,
        float* __restrict__ q, float* __restrict__ U, float* __restrict__ Z) {
    __shared__ float sn[64];
    int bs = blockIdx.x, d = threadIdx.x;
    float xv = slots[bs * 64 + d];
    float s1 = xv, s2 = xv * xv;
#pragma unroll
    for (int off = 1; off < 64; off <<= 1) {
        s1 += __shfl_xor(s1, off);
        s2 += __shfl_xor(s2, off);
    }
    float m = s1 * (1.f / 64.f);
    float inv = rsqrtf(s2 * (1.f / 64.f) - m * m + LN_EPS);
    sn[d] = (xv - m) * inv * lg[d] + lb[d];
    __syncthreads();
    float acc = 0.f;
#pragma unroll 8
    for (int i = 0; i < 64; ++i) acc += sn[i] * Wq[i * 64 + d];
    q[bs * 64 + d] = acc * 0.125f;
    U[bs * 64 + d] = 0.f;
    if (d == 0) Z[bs] = 0.f;
}

// ---------------- attn: MFMA logits + MFMA PV, vT tile staged in LDS ----------------
__global__ __launch_bounds__(256) void attn_kernel(
        const unsigned short* __restrict__ kp, const unsigned short* __restrict__ vtp,
        const float* __restrict__ q, float* __restrict__ U, float* __restrict__ Z) {
    __shared__ __align__(16) char smemraw[38912];
    unsigned short* vtile = (unsigned short*)smemraw;          // [64][264] bf16
    unsigned int* plds = (unsigned int*)(smemraw + 33792);     // [4][320]
    int t = threadIdx.x;
    int b = blockIdx.x >> 4, blk = blockIdx.x & 15;
    int w = t >> 6, lane = t & 63;
    int h = lane >> 4, c = lane & 15;
    // stage vT tile: 64 d x 256 n, coalesced 512B row segments
#pragma unroll
    for (int i = 0; i < 8; ++i) {
        int flat = (i * 256 + t) * 8;
        int dd = flat >> 8, noff = flat & 255;
        uint4 vv = *(const uint4*)(vtp + ((long)(b * 64 + dd)) * NN + blk * 256 + noff);
        *(uint4*)(&vtile[dd * 264 + noff]) = vv;
    }
    // q B-fragments (slot = c; zero for c >= 7)
    bf16x8 qf0, qf1;
    {
        int cs = (c < 7) ? c : 0;
        const float* qr = q + (b * NS + cs) * 64 + h * 8;
        float4 q0 = *(const float4*)(qr);
        float4 q1 = *(const float4*)(qr + 4);
        float4 q2 = *(const float4*)(qr + 32);
        float4 q3 = *(const float4*)(qr + 36);
        if (c >= 7) {
            q0 = make_float4(0.f, 0.f, 0.f, 0.f); q1 = q0; q2 = q0; q3 = q0;
        }
        qf0 = pack8(q0, q1);
        qf1 = pack8(q2, q3);
    }
    f32x4 pv[4];
#pragma unroll
    for (int i = 0; i < 4; ++i) pv[i] = (f32x4){0.f, 0.f, 0.f, 0.f};
    float zac = 0.f;
    unsigned int* pw = plds + w * 320;
    long rb0 = (long)b * NN + blk * 256 + w * 16;
    __syncthreads();
#pragma unroll
    for (int p = 0; p < 2; ++p) {
#pragma unroll
        for (int sh = 0; sh < 2; ++sh) {
            long rowbase = rb0 + p * 128 + sh * 64;
            const unsigned short* ka = kp + (rowbase + c) * 64 + h * 8;
            bf16x8 a0 = *(const bf16x8*)(ka);
            bf16x8 a1 = *(const bf16x8*)(ka + 32);
            f32x4 lg = (f32x4){0.f, 0.f, 0.f, 0.f};
            lg = __builtin_amdgcn_mfma_f32_16x16x32_bf16(a0, qf0, lg, 0, 0, 0);
            lg = __builtin_amdgcn_mfma_f32_16x16x32_bf16(a1, qf1, lg, 0, 0, 0);
            float av[4];
#pragma unroll
            for (int j = 0; j < 4; ++j) {
                float vl = (c < 7) ? lg[j] : -1e30f;
                float mx = vl;
                mx = fmaxf(mx, __shfl_xor(mx, 1));
                mx = fmaxf(mx, __shfl_xor(mx, 2));
                mx = fmaxf(mx, __shfl_xor(mx, 4));
                mx = fmaxf(mx, __shfl_xor(mx, 8));
                float e = (c < 7) ? __expf(lg[j] - mx) : 0.f;
                float se = e;
                se += __shfl_xor(se, 1);
                se += __shfl_xor(se, 2);
                se += __shfl_xor(se, 4);
                se += __shfl_xor(se, 8);
                float a = (c < 7) ? (__fdividef(e, se) + EPS_ATTN) : 0.f;
                av[j] = a;
                zac += a;
            }
            unsigned int w0 = (unsigned int)f2bf(av[0]) | ((unsigned int)f2bf(av[1]) << 16);
            unsigned int w1 = (unsigned int)f2bf(av[2]) | ((unsigned int)f2bf(av[3]) << 16);
            pw[c * 20 + sh * 8 + 2 * h]     = w0;
            pw[c * 20 + sh * 8 + 2 * h + 1] = w1;
        }
        // PV: A = P^T (rows=slots), B = V from LDS vT tile
        u32x4 pr = *(u32x4*)(&pw[c * 20 + 4 * h]);
        bf16x8 pa = __builtin_bit_cast(bf16x8, pr);
        int nloc = p * 128 + ((h < 2) ? (w * 16 + 8 * h) : (48 + w * 16 + 8 * h));
#pragma unroll
        for (int tile = 0; tile < 4; ++tile) {
            bf16x8 bv = *(const bf16x8*)(&vtile[(tile * 16 + c) * 264 + nloc]);
            pv[tile] = __builtin_amdgcn_mfma_f32_16x16x32_bf16(pa, bv, pv[tile], 0, 0, 0);
        }
    }
    // Z reduce
    zac += __shfl_xor(zac, 16);
    zac += __shfl_xor(zac, 32);
    if (h == 0 && c < 7) atomicAdd(Z + b * NS + c, zac);
    __syncthreads();   // before reusing vtile region for U reduction
    float* ured = (float*)smemraw;   // [4][512]
    if (h < 2) {
#pragma unroll
        for (int tile = 0; tile < 4; ++tile) {
#pragma unroll
            for (int j = 0; j < 4; ++j) {
                ured[w * 512 + (4 * h + j) * 64 + tile * 16 + c] = pv[tile][j];
            }
        }
    }
    __syncthreads();
    for (int idx = t; idx < NS * 64; idx += 256) {
        float tot = ured[idx] + ured[512 + idx] + ured[1024 + idx] + ured[1536 + idx];
        atomicAdd(U + b * NS * 64 + idx, tot);
    }
}

// ---------------- slots_post: batch-per-block; GRU, LN, MLP, next-iter q ----------------
__global__ __launch_bounds__(512) void slots_post_kernel(
        float* __restrict__ slots, float* __restrict__ U, float* __restrict__ Z,
        const float* __restrict__ gW, const float* __restrict__ gU, const float* __restrict__ gb,
        const float* __restrict__ lmg, const float* __restrict__ lmb,
        const float* __restrict__ W1, const float* __restrict__ b1,
        const float* __restrict__ W2, const float* __restrict__ b2,
        const float* __restrict__ Wq, const float* __restrict__ lsg, const float* __restrict__ lsb,
        float* __restrict__ q, float* __restrict__ outp, int last) {
    __shared__ float up[7][64], hp[7][64], hn[7][64], mm[7][64], sl[7][64], sn[7][64];
    __shared__ float hl[7][128];
    __shared__ float mxs[7][192], mhs[7][192];
    int bq = blockIdx.x;
    int t = threadIdx.x;
    int s = t >> 6, d = t & 63;
    if (t < 448) {
        int bs = bq * 7 + s;
        float zsum = Z[bs];
        up[s][d] = U[bs * 64 + d] / zsum;
        hp[s][d] = slots[bs * 64 + d];
        U[bs * 64 + d] = 0.f;
        if (d == 0) Z[bs] = 0.f;
    }
    __syncthreads();
    if (t < 192) {
        float acc[7];
#pragma unroll
        for (int s2 = 0; s2 < 7; ++s2) acc[s2] = gb[t];
#pragma unroll 4
        for (int i = 0; i < 64; ++i) {
            float wv = gW[i * 192 + t];
#pragma unroll
            for (int s2 = 0; s2 < 7; ++s2) acc[s2] += up[s2][i] * wv;
        }
#pragma unroll
        for (int s2 = 0; s2 < 7; ++s2) mxs[s2][t] = acc[s2];
    } else if (t >= 256 && t < 448) {
        int cc = t - 256;
        float acc[7];
#pragma unroll
        for (int s2 = 0; s2 < 7; ++s2) acc[s2] = gb[192 + cc];
#pragma unroll 4
        for (int i = 0; i < 64; ++i) {
            float wv = gU[i * 192 + cc];
#pragma unroll
            for (int s2 = 0; s2 < 7; ++s2) acc[s2] += hp[s2][i] * wv;
        }
#pragma unroll
        for (int s2 = 0; s2 < 7; ++s2) mhs[s2][cc] = acc[s2];
    }
    __syncthreads();
    if (t < 448) {
        float z = 1.f / (1.f + __expf(-(mxs[s][d] + mhs[s][d])));
        float r = 1.f / (1.f + __expf(-(mxs[s][64 + d] + mhs[s][64 + d])));
        float pre = mxs[s][128 + d] + r * mhs[s][128 + d];
        pre = fminf(fmaxf(pre, -15.f), 15.f);
        float e2 = __expf(2.f * pre);
        float hc = (e2 - 1.f) / (e2 + 1.f);
        float hnew = z * hp[s][d] + (1.f - z) * hc;
        hn[s][d] = hnew;
        float s1 = hnew, s2v = hnew * hnew;
#pragma unroll
        for (int off = 1; off < 64; off <<= 1) { s1 += __shfl_xor(s1, off); s2v += __shfl_xor(s2v, off); }
        float m = s1 * (1.f / 64.f);
        float inv = rsqrtf(s2v * (1.f / 64.f) - m * m + LN_EPS);
        mm[s][d] = (hnew - m) * inv * lmg[d] + lmb[d];
    }
    __syncthreads();
    if (t < 128) {
        float acc[7];
#pragma unroll
        for (int s2 = 0; s2 < 7; ++s2) acc[s2] = b1[t];
#pragma unroll 4
        for (int i = 0; i < 64; ++i) {
            float wv = W1[i * 128 + t];
#pragma unroll
            for (int s2 = 0; s2 < 7; ++s2) acc[s2] += mm[s2][i] * wv;
        }
#pragma unroll
        for (int s2 = 0; s2 < 7; ++s2) hl[s2][t] = fmaxf(acc[s2], 0.f);
    }
    __syncthreads();
    if (t < 64) {
        float acc[7];
#pragma unroll
        for (int s2 = 0; s2 < 7; ++s2) acc[s2] = hn[s2][t] + b2[t];
#pragma unroll 4
        for (int j = 0; j < 128; ++j) {
            float wv = W2[j * 64 + t];
#pragma unroll
            for (int s2 = 0; s2 < 7; ++s2) acc[s2] += hl[s2][j] * wv;
        }
#pragma unroll
        for (int s2 = 0; s2 < 7; ++s2) {
            int bs = bq * 7 + s2;
            slots[bs * 64 + t] = acc[s2];
            if (last) outp[bs * 64 + t] = acc[s2];
            sl[s2][t] = acc[s2];
        }
    }
    __syncthreads();
    if (t < 448) {
        float o = sl[s][d];
        float s1 = o, s2v = o * o;
#pragma unroll
        for (int off = 1; off < 64; off <<= 1) { s1 += __shfl_xor(s1, off); s2v += __shfl_xor(s2v, off); }
        float m = s1 * (1.f / 64.f);
        float inv = rsqrtf(s2v * (1.f / 64.f) - m * m + LN_EPS);
        sn[s][d] = (o - m) * inv * lsg[d] + lsb[d];
    }
    __syncthreads();
    if (t < 448) {
        float acc = 0.f;
#pragma unroll 8
        for (int i = 0; i < 64; ++i) acc += sn[s][i] * Wq[i * 64 + d];
        q[(bq * 7 + s) * 64 + d] = acc * 0.125f;
    }
}

extern "C" void kernel_launch(void* const* d_in, const int* in_sizes, int n_in,
                              void* d_out, int out_size, void* d_ws, size_t ws_size,
                              hipStream_t stream) {
    const float* inputs  = (const float*)d_in[0];
    const float* noise   = (const float*)d_in[1];
    const float* ln_in_g = (const float*)d_in[2];
    const float* ln_in_b = (const float*)d_in[3];
    const float* ln_s_g  = (const float*)d_in[4];
    const float* ln_s_b  = (const float*)d_in[5];
    const float* ln_m_g  = (const float*)d_in[6];
    const float* ln_m_b  = (const float*)d_in[7];
    const float* Wq      = (const float*)d_in[8];
    const float* Wk      = (const float*)d_in[9];
    const float* Wv      = (const float*)d_in[10];
    const float* mu      = (const float*)d_in[11];
    const float* lsig    = (const float*)d_in[12];
    const float* gW      = (const float*)d_in[13];
    const float* gU      = (const float*)d_in[14];
    const float* gb      = (const float*)d_in[15];
    const float* W1      = (const float*)d_in[16];
    const float* b1      = (const float*)d_in[17];
    const float* W2      = (const float*)d_in[18];
    const float* b2      = (const float*)d_in[19];

    char* ws = (char*)d_ws;
    unsigned short* kbuf = (unsigned short*)ws;                        // 32MB, [b][n][64]
    unsigned short* vtbuf = (unsigned short*)(ws + 33554432);          // 32MB, [b][64][4096]
    float* slots = (float*)(ws + 67108864);
    float* qbuf  = (float*)(ws + 67108864 + 114688);
    float* Ubuf  = (float*)(ws + 67108864 + 2 * 114688);
    float* Zbuf  = (float*)(ws + 67108864 + 3 * 114688);
    unsigned short* GkT = (unsigned short*)(ws + 67108864 + 3 * 114688 + 4096);
    unsigned short* GvT = GkT + 4096;
    float* cgk = (float*)(GvT + 4096);
    float* cbk = cgk + 64;
    float* cgv = cbk + 64;
    float* cbv = cgv + 64;

    prep_kernel<<<128, 64, 0, stream>>>(Wk, Wv, ln_in_g, ln_in_b, GkT, GvT, cgk, cbk, cgv, cbv);
    init_slots_kernel<<<112, 256, 0, stream>>>(noise, mu, lsig, slots);
    proj_kernel<<<2048, 256, 0, stream>>>(inputs, GkT, GvT, cgk, cbk, cgv, cbv, kbuf, vtbuf);
    slots_pre_kernel<<<448, 64, 0, stream>>>(slots, Wq, ln_s_g, ln_s_b, qbuf, Ubuf, Zbuf);
    for (int it = 0; it < 3; ++it) {
        attn_kernel<<<1024, 256, 0, stream>>>(kbuf, vtbuf, qbuf, Ubuf, Zbuf);
        slots_post_kernel<<<64, 512, 0, stream>>>(slots, Ubuf, Zbuf, gW, gU, gb,
                                                  ln_m_g, ln_m_b, W1, b1, W2, b2,
                                                  Wq, ln_s_g, ln_s_b, qbuf,
                                                  (float*)d_out, (it == 2) ? 1 : 0);
    }
}